// Round 1
// baseline (1667.318 us; speedup 1.0000x reference)
//
#include <hip/hip_runtime.h>
#include <cstdint>
#include <cstddef>

#define NB 4
#define NS 4096
#define ND 2048
#define NH 16
#define NHD 128
#define NT 1024
#define NF 8192

typedef __bf16 bf16;
typedef __bf16 bf16x8 __attribute__((ext_vector_type(8)));
typedef __bf16 bf16x4 __attribute__((ext_vector_type(4)));
typedef float  f32x4  __attribute__((ext_vector_type(4)));

__device__ __forceinline__ float wave_sum(float v) {
#pragma unroll
    for (int off = 32; off > 0; off >>= 1) v += __shfl_xor(v, off);
    return v;
}
__device__ __forceinline__ float wave_max(float v) {
#pragma unroll
    for (int off = 32; off > 0; off >>= 1) v = fmaxf(v, __shfl_xor(v, off));
    return v;
}

// ---------------------------------------------------------------------------
// Router: logits[row] = dot(x[row,:], w_router)   (row = b*NS+s)
// ---------------------------------------------------------------------------
__global__ __launch_bounds__(256) void router_k(const float* __restrict__ x,
                                                const float* __restrict__ wr,
                                                float* __restrict__ logits) {
    __shared__ float r4[4];
    long long row = blockIdx.x;
    const float4* xr = (const float4*)(x + row * ND);
    const float4* w4 = (const float4*)wr;
    float p = 0.f;
    for (int i = threadIdx.x; i < ND / 4; i += 256) {
        float4 a = xr[i], b = w4[i];
        p += a.x * b.x + a.y * b.y + a.z * b.z + a.w * b.w;
    }
    p = wave_sum(p);
    if ((threadIdx.x & 63) == 0) r4[threadIdx.x >> 6] = p;
    __syncthreads();
    if (threadIdx.x == 0) logits[row] = r4[0] + r4[1] + r4[2] + r4[3];
}

// ---------------------------------------------------------------------------
// Top-K (exact, matches jax.lax.top_k tie-break) + index sort + router softmax.
// One block of 1024 threads per batch; bitonic sorts in LDS.
// ---------------------------------------------------------------------------
__global__ __launch_bounds__(1024) void topk_k(const float* __restrict__ logits,
                                               int* __restrict__ sel,
                                               float* __restrict__ rw) {
    __shared__ unsigned long long keys[NS];   // 32 KB
    __shared__ float r16[16];
    __shared__ float bmax, bsum;
    const int bb = blockIdx.x;
    const int tid = threadIdx.x;
    const float* lg = logits + (long long)bb * NS;

    for (int i = tid; i < NS; i += 1024) {
        unsigned u = __float_as_uint(lg[i]);
        u = (u & 0x80000000u) ? ~u : (u | 0x80000000u);   // order-preserving map
        keys[i] = ((unsigned long long)u << 32) | (unsigned)(NS - 1 - i);
    }
    __syncthreads();
    // bitonic sort DESCENDING over 4096 (value major, low index wins ties)
    for (int k = 2; k <= NS; k <<= 1) {
        for (int j = k >> 1; j > 0; j >>= 1) {
            for (int i = tid; i < NS; i += 1024) {
                int ixj = i ^ j;
                if (ixj > i) {
                    unsigned long long a = keys[i], c = keys[ixj];
                    bool up = ((i & k) == 0);
                    if (up ? (a < c) : (a > c)) { keys[i] = c; keys[ixj] = a; }
                }
            }
            __syncthreads();
        }
    }
    // take top 1024, rebuild key = (idx<<32)|uval, sort ASCENDING by idx
    unsigned long long a0 = keys[tid];
    __syncthreads();
    {
        unsigned idx_ = NS - 1 - (unsigned)(a0 & 0xFFFFFFFFu);
        unsigned uval = (unsigned)(a0 >> 32);
        keys[tid] = ((unsigned long long)idx_ << 32) | uval;
    }
    __syncthreads();
    for (int k = 2; k <= NT; k <<= 1) {
        for (int j = k >> 1; j > 0; j >>= 1) {
            int i = tid, ixj = i ^ j;
            if (i < NT && ixj > i) {
                unsigned long long a = keys[i], c = keys[ixj];
                bool up = ((i & k) == 0);
                if (up ? (a > c) : (a < c)) { keys[i] = c; keys[ixj] = a; }
            }
            __syncthreads();
        }
    }
    unsigned long long kk = keys[tid];
    int si = (int)(kk >> 32);
    unsigned u = (unsigned)(kk & 0xFFFFFFFFu);
    u = (u & 0x80000000u) ? (u ^ 0x80000000u) : ~u;
    float val = __uint_as_float(u);

    const int wid = tid >> 6, lane = tid & 63;
    float mx = wave_max(val);
    if (lane == 0) r16[wid] = mx;
    __syncthreads();
    if (tid == 0) {
        float m = r16[0];
        for (int i = 1; i < 16; i++) m = fmaxf(m, r16[i]);
        bmax = m;
    }
    __syncthreads();
    float e = __expf(val - bmax);
    float s = wave_sum(e);
    if (lane == 0) r16[wid] = s;
    __syncthreads();
    if (tid == 0) {
        float t = 0.f;
        for (int i = 0; i < 16; i++) t += r16[i];
        bsum = t;
    }
    __syncthreads();
    sel[bb * NT + tid] = si;
    rw[bb * NT + tid] = e / bsum;
}

// ---------------------------------------------------------------------------
// Gather: xf[b,j,:] = x[b, sel[b,j], :]   (float4)
// ---------------------------------------------------------------------------
__global__ __launch_bounds__(256) void gather_k(const float* __restrict__ x,
                                                const int* __restrict__ sel,
                                                float* __restrict__ xf) {
    int gid = blockIdx.x * 256 + threadIdx.x;   // NB*NT*(ND/4) = 2^21
    int col = gid & (ND / 4 - 1);
    int row = gid >> 9;
    int bb = row >> 10;
    int s = sel[row];
    ((float4*)xf)[gid] = ((const float4*)x)[((long long)bb * NS + s) * (ND / 4) + col];
}

// ---------------------------------------------------------------------------
// RMSNorm row kernel: out = bf16(x * rsqrt(mean(x^2)+eps) * g)
// ---------------------------------------------------------------------------
__global__ __launch_bounds__(256) void rmsnorm_k(const float* __restrict__ x,
                                                 const float* __restrict__ g,
                                                 bf16* __restrict__ out) {
    __shared__ float r4[4];
    __shared__ float scl;
    long long row = blockIdx.x;
    const float4* xr = (const float4*)(x + row * ND);
    int i0 = threadIdx.x, i1 = threadIdx.x + 256;
    float4 a = xr[i0], b = xr[i1];
    float ss = a.x * a.x + a.y * a.y + a.z * a.z + a.w * a.w +
               b.x * b.x + b.y * b.y + b.z * b.z + b.w * b.w;
    ss = wave_sum(ss);
    if ((threadIdx.x & 63) == 0) r4[threadIdx.x >> 6] = ss;
    __syncthreads();
    if (threadIdx.x == 0)
        scl = rsqrtf((r4[0] + r4[1] + r4[2] + r4[3]) * (1.0f / ND) + 1e-6f);
    __syncthreads();
    float s = scl;
    const float4* g4 = (const float4*)g;
    float4 ga = g4[i0], gb = g4[i1];
    bf16x4 o0, o1;
    o0[0] = (bf16)(a.x * s * ga.x); o0[1] = (bf16)(a.y * s * ga.y);
    o0[2] = (bf16)(a.z * s * ga.z); o0[3] = (bf16)(a.w * s * ga.w);
    o1[0] = (bf16)(b.x * s * gb.x); o1[1] = (bf16)(b.y * s * gb.y);
    o1[2] = (bf16)(b.z * s * gb.z); o1[3] = (bf16)(b.w * s * gb.w);
    *(bf16x4*)(out + row * ND + i0 * 4) = o0;
    *(bf16x4*)(out + row * ND + i1 * 4) = o1;
}

// ---------------------------------------------------------------------------
// Transpose + fp32->bf16: out[c][r] = in[r][c]; in is R x C. dims %32 == 0.
// ---------------------------------------------------------------------------
__global__ __launch_bounds__(256) void transpose_to_bf16(const float* __restrict__ in,
                                                         bf16* __restrict__ out,
                                                         int R, int C) {
    __shared__ float tile[32][33];
    int bx = blockIdx.x * 32;   // col
    int by = blockIdx.y * 32;   // row
    int tx = threadIdx.x & 31;
    int ty = threadIdx.x >> 5;   // 0..7
#pragma unroll
    for (int i = 0; i < 4; i++)
        tile[ty + 8 * i][tx] = in[(long long)(by + ty + 8 * i) * C + bx + tx];
    __syncthreads();
#pragma unroll
    for (int i = 0; i < 4; i++)
        out[(long long)(bx + ty + 8 * i) * R + by + tx] = (bf16)tile[tx][ty + 8 * i];
}

// ---------------------------------------------------------------------------
// RoPE + layout shuffle: Qlin/Klin/Vlin [b][t][h*128+hd] ->
//   Q,K [b][h][t][hd] (rope applied), Vt [b][h][hd][t]
// ---------------------------------------------------------------------------
__global__ __launch_bounds__(256) void rope_k(const bf16* __restrict__ Qlin,
                                              const bf16* __restrict__ Klin,
                                              const bf16* __restrict__ Vlin,
                                              const float* __restrict__ fr,
                                              bf16* __restrict__ Q,
                                              bf16* __restrict__ K,
                                              bf16* __restrict__ Vt) {
    int gid = blockIdx.x * 256 + threadIdx.x;   // 2^22
    int hd = gid & 63;
    int h = (gid >> 6) & 15;
    int t = (gid >> 10) & (NT - 1);
    int bb = gid >> 20;
    float c = fr[t * 128 + hd * 2 + 0];
    float s = fr[t * 128 + hd * 2 + 1];
    long long base = ((long long)bb * NT + t) * ND + h * NHD;
    float q1 = (float)Qlin[base + hd], q2 = (float)Qlin[base + hd + 64];
    float k1 = (float)Klin[base + hd], k2 = (float)Klin[base + hd + 64];
    long long ob = (((long long)(bb * NH + h)) * NT + t) * NHD;
    Q[ob + hd]      = (bf16)(q1 * c - q2 * s);
    Q[ob + hd + 64] = (bf16)(q1 * s + q2 * c);
    K[ob + hd]      = (bf16)(k1 * c - k2 * s);
    K[ob + hd + 64] = (bf16)(k1 * s + k2 * c);
    long long vb = ((long long)(bb * NH + h)) * NHD * NT + t;
    Vt[vb + (long long)hd * NT]        = Vlin[base + hd];
    Vt[vb + (long long)(hd + 64) * NT] = Vlin[base + hd + 64];
}

// ---------------------------------------------------------------------------
// Row softmax (T=1024 cols): P = bf16(softmax(scores_row))
// ---------------------------------------------------------------------------
__global__ __launch_bounds__(256) void softmax_k(const float* __restrict__ Sc,
                                                 bf16* __restrict__ P) {
    __shared__ float r4[4];
    __shared__ float bc;
    long long row = blockIdx.x;   // h*NT + q
    float4 v = ((const float4*)(Sc + row * NT))[threadIdx.x];
    float mx = fmaxf(fmaxf(v.x, v.y), fmaxf(v.z, v.w));
    mx = wave_max(mx);
    if ((threadIdx.x & 63) == 0) r4[threadIdx.x >> 6] = mx;
    __syncthreads();
    if (threadIdx.x == 0) bc = fmaxf(fmaxf(r4[0], r4[1]), fmaxf(r4[2], r4[3]));
    __syncthreads();
    float m = bc;
    float e0 = __expf(v.x - m), e1 = __expf(v.y - m);
    float e2 = __expf(v.z - m), e3 = __expf(v.w - m);
    float ss = wave_sum(e0 + e1 + e2 + e3);
    if ((threadIdx.x & 63) == 0) r4[threadIdx.x >> 6] = ss;
    __syncthreads();
    if (threadIdx.x == 0) bc = 1.f / (r4[0] + r4[1] + r4[2] + r4[3]);
    __syncthreads();
    float inv = bc;
    bf16x4 o;
    o[0] = (bf16)(e0 * inv); o[1] = (bf16)(e1 * inv);
    o[2] = (bf16)(e2 * inv); o[3] = (bf16)(e3 * inv);
    *(bf16x4*)(P + row * NT + threadIdx.x * 4) = o;
}

// ---------------------------------------------------------------------------
// Copy x -> out (float4 grid-stride)
// ---------------------------------------------------------------------------
__global__ __launch_bounds__(256) void copy_k(const float4* __restrict__ in,
                                              float4* __restrict__ out, long long n) {
    for (long long i = (long long)blockIdx.x * 256 + threadIdx.x; i < n;
         i += (long long)gridDim.x * 256)
        out[i] = in[i];
}

// ---------------------------------------------------------------------------
// MFMA GEMM: C(MxN) = A(MxK) . Bt(NxK)^T, bf16 in, fp32 accum.
// 128x128 block tile, 4 waves (2x2), 16x16x32 bf16 MFMA, 4x4 frags/wave.
// MODE 0: C bf16 = alpha*acc           (ldc, z-stride in elems)
// MODE 1: C fp32 = alpha*acc
// MODE 2: C fp32 += acc                 (in-place residual)
// MODE 3: C bf16 = silu(acc)
// MODE 4: C bf16 *= acc                 (in-place gated mul)
// MODE 5: scatter: out[(b*NS+sel[m])*ND+n] += rw[m]*(res[m*ND+n]+acc)
// All of M,N %128==0 and K %32==0 (guaranteed by problem shapes).
// ---------------------------------------------------------------------------
template <int MODE>
__global__ __launch_bounds__(256, 2) void gemm_bt(
    const bf16* __restrict__ A, int lda, long long sAz,
    const bf16* __restrict__ Bt, int ldb, long long sBz,
    void* __restrict__ Cv, long long sCz, int ldc,
    int K, float alpha,
    const float* __restrict__ res, const int* __restrict__ selp,
    const float* __restrict__ rwp, float* __restrict__ outp) {
    __shared__ bf16 As[128][40];
    __shared__ bf16 Bs[128][40];

    const int tid = threadIdx.x;
    const int lane = tid & 63;
    const int wave = tid >> 6;
    const int wm = wave >> 1, wn = wave & 1;
    const int lm = lane & 15, lq = lane >> 4;

    const int m0 = blockIdx.y * 128;
    const int n0 = blockIdx.x * 128;
    const int z = blockIdx.z;

    A += (long long)z * sAz;
    Bt += (long long)z * sBz;

    f32x4 acc[4][4];
#pragma unroll
    for (int i = 0; i < 4; i++)
#pragma unroll
        for (int j = 0; j < 4; j++) {
            f32x4 zz = {0.f, 0.f, 0.f, 0.f};
            acc[i][j] = zz;
        }

    const int c0 = tid, c1 = tid + 256;
    const int am0 = c0 >> 2, ak0 = (c0 & 3) * 8;
    const int am1 = c1 >> 2, ak1 = (c1 & 3) * 8;

    for (int k0 = 0; k0 < K; k0 += 32) {
        bf16x8 a0 = *(const bf16x8*)(A + (long long)(m0 + am0) * lda + k0 + ak0);
        bf16x8 a1 = *(const bf16x8*)(A + (long long)(m0 + am1) * lda + k0 + ak1);
        bf16x8 b0 = *(const bf16x8*)(Bt + (long long)(n0 + am0) * ldb + k0 + ak0);
        bf16x8 b1 = *(const bf16x8*)(Bt + (long long)(n0 + am1) * ldb + k0 + ak1);
        __syncthreads();
        *(bf16x8*)&As[am0][ak0] = a0;
        *(bf16x8*)&As[am1][ak1] = a1;
        *(bf16x8*)&Bs[am0][ak0] = b0;
        *(bf16x8*)&Bs[am1][ak1] = b1;
        __syncthreads();

        bf16x8 af[4], bfr[4];
#pragma unroll
        for (int mi = 0; mi < 4; mi++)
            af[mi] = *(const bf16x8*)&As[wm * 64 + mi * 16 + lm][lq * 8];
#pragma unroll
        for (int ni = 0; ni < 4; ni++)
            bfr[ni] = *(const bf16x8*)&Bs[wn * 64 + ni * 16 + lm][lq * 8];
#pragma unroll
        for (int mi = 0; mi < 4; mi++)
#pragma unroll
            for (int ni = 0; ni < 4; ni++)
                acc[mi][ni] = __builtin_amdgcn_mfma_f32_16x16x32_bf16(
                    af[mi], bfr[ni], acc[mi][ni], 0, 0, 0);
    }

#pragma unroll
    for (int mi = 0; mi < 4; mi++) {
#pragma unroll
        for (int ni = 0; ni < 4; ni++) {
            int row = m0 + wm * 64 + mi * 16 + lq * 4;
            int col = n0 + wn * 64 + ni * 16 + lm;
#pragma unroll
            for (int r = 0; r < 4; r++) {
                float v = alpha * acc[mi][ni][r];
                long long rr = row + r;
                if constexpr (MODE == 0) {
                    bf16* C = (bf16*)Cv + (long long)z * sCz;
                    C[rr * ldc + col] = (bf16)v;
                } else if constexpr (MODE == 1) {
                    float* C = (float*)Cv + (long long)z * sCz;
                    C[rr * ldc + col] = v;
                } else if constexpr (MODE == 2) {
                    float* C = (float*)Cv;
                    C[rr * ldc + col] += v;
                } else if constexpr (MODE == 3) {
                    bf16* C = (bf16*)Cv;
                    C[rr * ldc + col] = (bf16)(v / (1.f + __expf(-v)));
                } else if constexpr (MODE == 4) {
                    bf16* C = (bf16*)Cv;
                    bf16* p = &C[rr * ldc + col];
                    *p = (bf16)((float)*p * v);
                } else {   // MODE 5
                    int bb = (int)(rr >> 10);
                    int s = selp[rr];
                    float* p = outp + ((long long)bb * NS + s) * ND + col;
                    *p += rwp[rr] * (res[rr * (long long)ND + col] + v);
                }
            }
        }
    }
}

// ---------------------------------------------------------------------------
extern "C" void kernel_launch(void* const* d_in, const int* in_sizes, int n_in,
                              void* d_out, int out_size, void* d_ws, size_t ws_size,
                              hipStream_t stream) {
    const float* x  = (const float*)d_in[0];
    // d_in[1] = mask (all zeros) -- unused
    const float* fr = (const float*)d_in[2];
    const float* wr = (const float*)d_in[3];
    const float* g1 = (const float*)d_in[4];
    const float* wq = (const float*)d_in[5];
    const float* wk = (const float*)d_in[6];
    const float* wv = (const float*)d_in[7];
    const float* wo = (const float*)d_in[8];
    const float* g2 = (const float*)d_in[9];
    const float* w1 = (const float*)d_in[10];
    const float* w3 = (const float*)d_in[11];
    const float* w2 = (const float*)d_in[12];
    float* out = (float*)d_out;

    char* ws = (char*)d_ws;
    size_t off = 0;
    auto take = [&](size_t bytes) -> char* {
        char* p = ws + off;
        off += (bytes + 255) & ~(size_t)255;
        return p;
    };
    int*   sel    = (int*)take((size_t)NB * NT * 4);
    float* rw     = (float*)take((size_t)NB * NT * 4);
    float* logits = (float*)take((size_t)NB * NS * 4);
    float* xf     = (float*)take((size_t)NB * NT * ND * 4);
    bf16*  hbuf   = (bf16*)take((size_t)NB * NT * ND * 2);
    bf16*  wq_t   = (bf16*)take((size_t)ND * ND * 2);
    bf16*  wk_t   = (bf16*)take((size_t)ND * ND * 2);
    bf16*  wv_t   = (bf16*)take((size_t)ND * ND * 2);
    bf16*  wo_t   = (bf16*)take((size_t)ND * ND * 2);
    bf16*  Obuf   = (bf16*)take((size_t)NB * NT * ND * 2);
    // X/Y overlay region (attention scratch, then FFN scratch)
    char* xr = ws + off;
    bf16* Qlin = (bf16*)xr;
    bf16* Klin = Qlin + (size_t)NB * NT * ND;
    bf16* Vlin = Klin + (size_t)NB * NT * ND;
    bf16* Qr   = Vlin + (size_t)NB * NT * ND;
    bf16* Kr   = Qr + (size_t)NB * NT * ND;
    bf16* Vt   = Kr + (size_t)NB * NT * ND;
    float* scores = (float*)(Vt + (size_t)NB * NT * ND);
    bf16*  P      = (bf16*)(scores + (size_t)NH * NT * NT);
    // Y overlay (valid once attention is done):
    bf16* w1_t  = (bf16*)xr;
    bf16* w3_t  = w1_t + (size_t)ND * NF;
    bf16* w2_t  = w3_t + (size_t)ND * NF;
    bf16* inter = w2_t + (size_t)ND * NF;

    // 1. router + topk + gather + rmsnorm1
    router_k<<<NB * NS, 256, 0, stream>>>(x, wr, logits);
    topk_k<<<NB, 1024, 0, stream>>>(logits, sel, rw);
    gather_k<<<(NB * NT * ND / 4) / 256, 256, 0, stream>>>(x, sel, xf);
    rmsnorm_k<<<NB * NT, 256, 0, stream>>>(xf, g1, hbuf);

    // 2. weight prep (attention)
    dim3 tg(ND / 32, ND / 32);
    transpose_to_bf16<<<tg, 256, 0, stream>>>(wq, wq_t, ND, ND);
    transpose_to_bf16<<<tg, 256, 0, stream>>>(wk, wk_t, ND, ND);
    transpose_to_bf16<<<tg, 256, 0, stream>>>(wv, wv_t, ND, ND);
    transpose_to_bf16<<<tg, 256, 0, stream>>>(wo, wo_t, ND, ND);

    // 3. QKV projections
    dim3 gp(ND / 128, (NB * NT) / 128, 1);
    gemm_bt<0><<<gp, 256, 0, stream>>>(hbuf, ND, 0, wq_t, ND, 0, Qlin, 0, ND,
                                       ND, 1.0f, nullptr, nullptr, nullptr, nullptr);
    gemm_bt<0><<<gp, 256, 0, stream>>>(hbuf, ND, 0, wk_t, ND, 0, Klin, 0, ND,
                                       ND, 1.0f, nullptr, nullptr, nullptr, nullptr);
    gemm_bt<0><<<gp, 256, 0, stream>>>(hbuf, ND, 0, wv_t, ND, 0, Vlin, 0, ND,
                                       ND, 1.0f, nullptr, nullptr, nullptr, nullptr);
    rope_k<<<(NB * NT * NH * 64) / 256, 256, 0, stream>>>(Qlin, Klin, Vlin, fr,
                                                          Qr, Kr, Vt);

    // 4. attention (per batch to bound scratch)
    const float scal = 0.08838834764831845f;   // 1/sqrt(128)
    for (int bb = 0; bb < NB; bb++) {
        dim3 gs(NT / 128, NT / 128, NH);
        gemm_bt<1><<<gs, 256, 0, stream>>>(
            Qr + (size_t)bb * NH * NT * NHD, NHD, (long long)NT * NHD,
            Kr + (size_t)bb * NH * NT * NHD, NHD, (long long)NT * NHD,
            scores, (long long)NT * NT, NT, NHD, scal,
            nullptr, nullptr, nullptr, nullptr);
        softmax_k<<<NH * NT, 256, 0, stream>>>(scores, P);
        dim3 gv(NHD / 128, NT / 128, NH);
        gemm_bt<0><<<gv, 256, 0, stream>>>(
            P, NT, (long long)NT * NT,
            Vt + (size_t)bb * NH * NHD * NT, NT, (long long)NHD * NT,
            Obuf + (size_t)bb * NT * ND, NHD, ND, NT, 1.0f,
            nullptr, nullptr, nullptr, nullptr);
    }

    // 5. o-proj with residual into xf (x1 = xf + O @ wo)
    gemm_bt<2><<<gp, 256, 0, stream>>>(Obuf, ND, 0, wo_t, ND, 0, xf, 0, ND,
                                       ND, 1.0f, nullptr, nullptr, nullptr, nullptr);

    // 6. rmsnorm2 -> hbuf (reuse)
    rmsnorm_k<<<NB * NT, 256, 0, stream>>>(xf, g2, hbuf);

    // 7. FFN weight prep (Y region; attention scratch dead)
    transpose_to_bf16<<<dim3(NF / 32, ND / 32), 256, 0, stream>>>(w1, w1_t, ND, NF);
    transpose_to_bf16<<<dim3(NF / 32, ND / 32), 256, 0, stream>>>(w3, w3_t, ND, NF);
    transpose_to_bf16<<<dim3(ND / 32, NF / 32), 256, 0, stream>>>(w2, w2_t, NF, ND);

    // 8. FFN: inter = silu(h2@w1) * (h2@w3)
    dim3 gf(NF / 128, (NB * NT) / 128, 1);
    gemm_bt<3><<<gf, 256, 0, stream>>>(hbuf, ND, 0, w1_t, ND, 0, inter, 0, NF,
                                       ND, 1.0f, nullptr, nullptr, nullptr, nullptr);
    gemm_bt<4><<<gf, 256, 0, stream>>>(hbuf, ND, 0, w3_t, ND, 0, inter, 0, NF,
                                       ND, 1.0f, nullptr, nullptr, nullptr, nullptr);

    // 9. out = x everywhere; then fused FFN2 + scatter-add of selected rows
    copy_k<<<8192, 256, 0, stream>>>((const float4*)x, (float4*)out,
                                     (long long)NB * NS * ND / 4);
    gemm_bt<5><<<gp, 256, 0, stream>>>(inter, NF, 0, w2_t, NF, 0, nullptr, 0, ND,
                                       NF, 1.0f, xf, sel, rw, out);
}

// Round 2
// 1644.121 us; speedup vs baseline: 1.0141x; 1.0141x over previous
//
#include <hip/hip_runtime.h>
#include <cstdint>
#include <cstddef>

#define NB 4
#define NS 4096
#define ND 2048
#define NH 16
#define NHD 128
#define NT 1024
#define NF 8192

typedef __bf16 bf16;
typedef __bf16 bf16x8 __attribute__((ext_vector_type(8)));
typedef __bf16 bf16x4 __attribute__((ext_vector_type(4)));
typedef float  f32x4  __attribute__((ext_vector_type(4)));

typedef const __attribute__((address_space(1))) void* gptr_t;
typedef __attribute__((address_space(3))) void* lptr_t;

__device__ __forceinline__ float wave_sum(float v) {
#pragma unroll
    for (int off = 32; off > 0; off >>= 1) v += __shfl_xor(v, off);
    return v;
}
__device__ __forceinline__ float wave_max(float v) {
#pragma unroll
    for (int off = 32; off > 0; off >>= 1) v = fmaxf(v, __shfl_xor(v, off));
    return v;
}

// ---------------------------------------------------------------------------
// Router: logits[row] = dot(x[row,:], w_router)   (row = b*NS+s)
// ---------------------------------------------------------------------------
__global__ __launch_bounds__(256) void router_k(const float* __restrict__ x,
                                                const float* __restrict__ wr,
                                                float* __restrict__ logits) {
    __shared__ float r4[4];
    long long row = blockIdx.x;
    const float4* xr = (const float4*)(x + row * ND);
    const float4* w4 = (const float4*)wr;
    float p = 0.f;
    for (int i = threadIdx.x; i < ND / 4; i += 256) {
        float4 a = xr[i], b = w4[i];
        p += a.x * b.x + a.y * b.y + a.z * b.z + a.w * b.w;
    }
    p = wave_sum(p);
    if ((threadIdx.x & 63) == 0) r4[threadIdx.x >> 6] = p;
    __syncthreads();
    if (threadIdx.x == 0) logits[row] = r4[0] + r4[1] + r4[2] + r4[3];
}

// ---------------------------------------------------------------------------
// Top-K (exact, matches jax.lax.top_k tie-break) + index sort + router softmax.
// ---------------------------------------------------------------------------
__global__ __launch_bounds__(1024) void topk_k(const float* __restrict__ logits,
                                               int* __restrict__ sel,
                                               float* __restrict__ rw) {
    __shared__ unsigned long long keys[NS];   // 32 KB
    __shared__ float r16[16];
    __shared__ float bmax, bsum;
    const int bb = blockIdx.x;
    const int tid = threadIdx.x;
    const float* lg = logits + (long long)bb * NS;

    for (int i = tid; i < NS; i += 1024) {
        unsigned u = __float_as_uint(lg[i]);
        u = (u & 0x80000000u) ? ~u : (u | 0x80000000u);   // order-preserving map
        keys[i] = ((unsigned long long)u << 32) | (unsigned)(NS - 1 - i);
    }
    __syncthreads();
    for (int k = 2; k <= NS; k <<= 1) {
        for (int j = k >> 1; j > 0; j >>= 1) {
            for (int i = tid; i < NS; i += 1024) {
                int ixj = i ^ j;
                if (ixj > i) {
                    unsigned long long a = keys[i], c = keys[ixj];
                    bool up = ((i & k) == 0);
                    if (up ? (a < c) : (a > c)) { keys[i] = c; keys[ixj] = a; }
                }
            }
            __syncthreads();
        }
    }
    unsigned long long a0 = keys[tid];
    __syncthreads();
    {
        unsigned idx_ = NS - 1 - (unsigned)(a0 & 0xFFFFFFFFu);
        unsigned uval = (unsigned)(a0 >> 32);
        keys[tid] = ((unsigned long long)idx_ << 32) | uval;
    }
    __syncthreads();
    for (int k = 2; k <= NT; k <<= 1) {
        for (int j = k >> 1; j > 0; j >>= 1) {
            int i = tid, ixj = i ^ j;
            if (i < NT && ixj > i) {
                unsigned long long a = keys[i], c = keys[ixj];
                bool up = ((i & k) == 0);
                if (up ? (a > c) : (a < c)) { keys[i] = c; keys[ixj] = a; }
            }
            __syncthreads();
        }
    }
    unsigned long long kk = keys[tid];
    int si = (int)(kk >> 32);
    unsigned u = (unsigned)(kk & 0xFFFFFFFFu);
    u = (u & 0x80000000u) ? (u ^ 0x80000000u) : ~u;
    float val = __uint_as_float(u);

    const int wid = tid >> 6, lane = tid & 63;
    float mx = wave_max(val);
    if (lane == 0) r16[wid] = mx;
    __syncthreads();
    if (tid == 0) {
        float m = r16[0];
        for (int i = 1; i < 16; i++) m = fmaxf(m, r16[i]);
        bmax = m;
    }
    __syncthreads();
    float e = __expf(val - bmax);
    float s = wave_sum(e);
    if (lane == 0) r16[wid] = s;
    __syncthreads();
    if (tid == 0) {
        float t = 0.f;
        for (int i = 0; i < 16; i++) t += r16[i];
        bsum = t;
    }
    __syncthreads();
    sel[bb * NT + tid] = si;
    rw[bb * NT + tid] = e / bsum;
}

// ---------------------------------------------------------------------------
// Gather: xf[b,j,:] = x[b, sel[b,j], :]   (float4)
// ---------------------------------------------------------------------------
__global__ __launch_bounds__(256) void gather_k(const float* __restrict__ x,
                                                const int* __restrict__ sel,
                                                float* __restrict__ xf) {
    int gid = blockIdx.x * 256 + threadIdx.x;
    int col = gid & (ND / 4 - 1);
    int row = gid >> 9;
    int bb = row >> 10;
    int s = sel[row];
    ((float4*)xf)[gid] = ((const float4*)x)[((long long)bb * NS + s) * (ND / 4) + col];
}

// ---------------------------------------------------------------------------
// RMSNorm row kernel: out = bf16(x * rsqrt(mean(x^2)+eps) * g)
// ---------------------------------------------------------------------------
__global__ __launch_bounds__(256) void rmsnorm_k(const float* __restrict__ x,
                                                 const float* __restrict__ g,
                                                 bf16* __restrict__ out) {
    __shared__ float r4[4];
    __shared__ float scl;
    long long row = blockIdx.x;
    const float4* xr = (const float4*)(x + row * ND);
    int i0 = threadIdx.x, i1 = threadIdx.x + 256;
    float4 a = xr[i0], b = xr[i1];
    float ss = a.x * a.x + a.y * a.y + a.z * a.z + a.w * a.w +
               b.x * b.x + b.y * b.y + b.z * b.z + b.w * b.w;
    ss = wave_sum(ss);
    if ((threadIdx.x & 63) == 0) r4[threadIdx.x >> 6] = ss;
    __syncthreads();
    if (threadIdx.x == 0)
        scl = rsqrtf((r4[0] + r4[1] + r4[2] + r4[3]) * (1.0f / ND) + 1e-6f);
    __syncthreads();
    float s = scl;
    const float4* g4 = (const float4*)g;
    float4 ga = g4[i0], gb = g4[i1];
    bf16x4 o0, o1;
    o0[0] = (bf16)(a.x * s * ga.x); o0[1] = (bf16)(a.y * s * ga.y);
    o0[2] = (bf16)(a.z * s * ga.z); o0[3] = (bf16)(a.w * s * ga.w);
    o1[0] = (bf16)(b.x * s * gb.x); o1[1] = (bf16)(b.y * s * gb.y);
    o1[2] = (bf16)(b.z * s * gb.z); o1[3] = (bf16)(b.w * s * gb.w);
    *(bf16x4*)(out + row * ND + i0 * 4) = o0;
    *(bf16x4*)(out + row * ND + i1 * 4) = o1;
}

// ---------------------------------------------------------------------------
// Transpose + fp32->bf16: out[c][r] = in[r][c]; in is R x C. dims %32 == 0.
// ---------------------------------------------------------------------------
__global__ __launch_bounds__(256) void transpose_to_bf16(const float* __restrict__ in,
                                                         bf16* __restrict__ out,
                                                         int R, int C) {
    __shared__ float tile[32][33];
    int bx = blockIdx.x * 32;   // col
    int by = blockIdx.y * 32;   // row
    int tx = threadIdx.x & 31;
    int ty = threadIdx.x >> 5;   // 0..7
#pragma unroll
    for (int i = 0; i < 4; i++)
        tile[ty + 8 * i][tx] = in[(long long)(by + ty + 8 * i) * C + bx + tx];
    __syncthreads();
#pragma unroll
    for (int i = 0; i < 4; i++)
        out[(long long)(bx + ty + 8 * i) * R + by + tx] = (bf16)tile[tx][ty + 8 * i];
}

// ---------------------------------------------------------------------------
// RoPE + layout shuffle
// ---------------------------------------------------------------------------
__global__ __launch_bounds__(256) void rope_k(const bf16* __restrict__ Qlin,
                                              const bf16* __restrict__ Klin,
                                              const bf16* __restrict__ Vlin,
                                              const float* __restrict__ fr,
                                              bf16* __restrict__ Q,
                                              bf16* __restrict__ K,
                                              bf16* __restrict__ Vt) {
    int gid = blockIdx.x * 256 + threadIdx.x;
    int hd = gid & 63;
    int h = (gid >> 6) & 15;
    int t = (gid >> 10) & (NT - 1);
    int bb = gid >> 20;
    float c = fr[t * 128 + hd * 2 + 0];
    float s = fr[t * 128 + hd * 2 + 1];
    long long base = ((long long)bb * NT + t) * ND + h * NHD;
    float q1 = (float)Qlin[base + hd], q2 = (float)Qlin[base + hd + 64];
    float k1 = (float)Klin[base + hd], k2 = (float)Klin[base + hd + 64];
    long long ob = (((long long)(bb * NH + h)) * NT + t) * NHD;
    Q[ob + hd]      = (bf16)(q1 * c - q2 * s);
    Q[ob + hd + 64] = (bf16)(q1 * s + q2 * c);
    K[ob + hd]      = (bf16)(k1 * c - k2 * s);
    K[ob + hd + 64] = (bf16)(k1 * s + k2 * c);
    long long vb = ((long long)(bb * NH + h)) * NHD * NT + t;
    Vt[vb + (long long)hd * NT]        = Vlin[base + hd];
    Vt[vb + (long long)(hd + 64) * NT] = Vlin[base + hd + 64];
}

// ---------------------------------------------------------------------------
// Row softmax (T=1024 cols): P = bf16(softmax(scores_row))
// ---------------------------------------------------------------------------
__global__ __launch_bounds__(256) void softmax_k(const float* __restrict__ Sc,
                                                 bf16* __restrict__ P) {
    __shared__ float r4[4];
    __shared__ float bc;
    long long row = blockIdx.x;
    float4 v = ((const float4*)(Sc + row * NT))[threadIdx.x];
    float mx = fmaxf(fmaxf(v.x, v.y), fmaxf(v.z, v.w));
    mx = wave_max(mx);
    if ((threadIdx.x & 63) == 0) r4[threadIdx.x >> 6] = mx;
    __syncthreads();
    if (threadIdx.x == 0) bc = fmaxf(fmaxf(r4[0], r4[1]), fmaxf(r4[2], r4[3]));
    __syncthreads();
    float m = bc;
    float e0 = __expf(v.x - m), e1 = __expf(v.y - m);
    float e2 = __expf(v.z - m), e3 = __expf(v.w - m);
    float ss = wave_sum(e0 + e1 + e2 + e3);
    if ((threadIdx.x & 63) == 0) r4[threadIdx.x >> 6] = ss;
    __syncthreads();
    if (threadIdx.x == 0) bc = 1.f / (r4[0] + r4[1] + r4[2] + r4[3]);
    __syncthreads();
    float inv = bc;
    bf16x4 o;
    o[0] = (bf16)(e0 * inv); o[1] = (bf16)(e1 * inv);
    o[2] = (bf16)(e2 * inv); o[3] = (bf16)(e3 * inv);
    *(bf16x4*)(P + row * NT + threadIdx.x * 4) = o;
}

// ---------------------------------------------------------------------------
__global__ __launch_bounds__(256) void copy_k(const float4* __restrict__ in,
                                              float4* __restrict__ out, long long n) {
    for (long long i = (long long)blockIdx.x * 256 + threadIdx.x; i < n;
         i += (long long)gridDim.x * 256)
        out[i] = in[i];
}

// ---------------------------------------------------------------------------
// MFMA GEMM (m97 structure): C(MxN) = A(MxK) . Bt(NxK)^T, bf16 in, fp32 accum.
// 128x128 tile, 4 waves (2x2), 16x16x32 MFMA, global_load_lds width=16
// staging into UNPADDED As/Bs[128][32] (lane-sequential layout requirement).
// MODE 0: C bf16 = alpha*acc     MODE 1: C fp32 = alpha*acc
// MODE 2: C fp32 += acc          MODE 3: C bf16 = silu(acc)
// MODE 4: C bf16 *= acc          MODE 5: out[(b*NS+sel[m])*ND+n] += rw[m]*(res+acc)
// ---------------------------------------------------------------------------
template <int MODE>
__global__ __launch_bounds__(256, 2) void gemm_bt(
    const bf16* __restrict__ A, int lda, long long sAz,
    const bf16* __restrict__ Bt, int ldb, long long sBz,
    void* __restrict__ Cv, long long sCz, int ldc,
    int K, float alpha,
    const float* __restrict__ res, const int* __restrict__ selp,
    const float* __restrict__ rwp, float* __restrict__ outp) {
    __shared__ bf16 As[128][32];   // 8 KB, unpadded (global_load_lds layout)
    __shared__ bf16 Bs[128][32];

    const int tid = threadIdx.x;
    const int lane = tid & 63;
    const int wave = tid >> 6;
    const int wm = wave >> 1, wn = wave & 1;
    const int lm = lane & 15, lq = lane >> 4;

    const int m0 = blockIdx.y * 128;
    const int n0 = blockIdx.x * 128;
    const int z = blockIdx.z;

    A += (long long)z * sAz;
    Bt += (long long)z * sBz;

    f32x4 acc[4][4];
#pragma unroll
    for (int i = 0; i < 4; i++)
#pragma unroll
        for (int j = 0; j < 4; j++) {
            f32x4 zz = {0.f, 0.f, 0.f, 0.f};
            acc[i][j] = zz;
        }

    // staging coords: wave w stages rows w*16+(lane>>2) and +64; 4 lanes/row,
    // each lane 8 bf16 (16 B). LDS dest is exactly base + lane*16 (sequential).
    const int sr = wave * 16 + (lane >> 2);
    const int sk = (lane & 3) * 8;
    const bf16* gA0 = A + (long long)(m0 + sr) * lda + sk;
    const bf16* gA1 = gA0 + (long long)64 * lda;
    const bf16* gB0 = Bt + (long long)(n0 + sr) * ldb + sk;
    const bf16* gB1 = gB0 + (long long)64 * ldb;
    bf16* lA0 = &As[sr][sk];
    bf16* lA1 = &As[sr + 64][sk];
    bf16* lB0 = &Bs[sr][sk];
    bf16* lB1 = &Bs[sr + 64][sk];

    for (int k0 = 0; k0 < K; k0 += 32) {
        __builtin_amdgcn_global_load_lds((gptr_t)(gA0 + k0), (lptr_t)lA0, 16, 0, 0);
        __builtin_amdgcn_global_load_lds((gptr_t)(gA1 + k0), (lptr_t)lA1, 16, 0, 0);
        __builtin_amdgcn_global_load_lds((gptr_t)(gB0 + k0), (lptr_t)lB0, 16, 0, 0);
        __builtin_amdgcn_global_load_lds((gptr_t)(gB1 + k0), (lptr_t)lB1, 16, 0, 0);
        __syncthreads();   // drains vmcnt(0): staged tile visible

        bf16x8 af[4], bfr[4];
#pragma unroll
        for (int mi = 0; mi < 4; mi++)
            af[mi] = *(const bf16x8*)&As[wm * 64 + mi * 16 + lm][lq * 8];
#pragma unroll
        for (int ni = 0; ni < 4; ni++)
            bfr[ni] = *(const bf16x8*)&Bs[wn * 64 + ni * 16 + lm][lq * 8];
#pragma unroll
        for (int mi = 0; mi < 4; mi++)
#pragma unroll
            for (int ni = 0; ni < 4; ni++)
                acc[mi][ni] = __builtin_amdgcn_mfma_f32_16x16x32_bf16(
                    af[mi], bfr[ni], acc[mi][ni], 0, 0, 0);
        __syncthreads();   // all waves done reading before next overwrite
    }

#pragma unroll
    for (int mi = 0; mi < 4; mi++) {
#pragma unroll
        for (int ni = 0; ni < 4; ni++) {
            int row = m0 + wm * 64 + mi * 16 + lq * 4;
            int col = n0 + wn * 64 + ni * 16 + lm;
#pragma unroll
            for (int r = 0; r < 4; r++) {
                float v = alpha * acc[mi][ni][r];
                long long rr = row + r;
                if constexpr (MODE == 0) {
                    bf16* C = (bf16*)Cv + (long long)z * sCz;
                    C[rr * ldc + col] = (bf16)v;
                } else if constexpr (MODE == 1) {
                    float* C = (float*)Cv + (long long)z * sCz;
                    C[rr * ldc + col] = v;
                } else if constexpr (MODE == 2) {
                    float* C = (float*)Cv;
                    C[rr * ldc + col] += v;
                } else if constexpr (MODE == 3) {
                    bf16* C = (bf16*)Cv;
                    C[rr * ldc + col] = (bf16)(v / (1.f + __expf(-v)));
                } else if constexpr (MODE == 4) {
                    bf16* C = (bf16*)Cv;
                    bf16* p = &C[rr * ldc + col];
                    *p = (bf16)((float)*p * v);
                } else {   // MODE 5
                    int bb = (int)(rr >> 10);
                    int s = selp[rr];
                    float* p = outp + ((long long)bb * NS + s) * ND + col;
                    *p += rwp[rr] * (res[rr * (long long)ND + col] + v);
                }
            }
        }
    }
}

// ---------------------------------------------------------------------------
extern "C" void kernel_launch(void* const* d_in, const int* in_sizes, int n_in,
                              void* d_out, int out_size, void* d_ws, size_t ws_size,
                              hipStream_t stream) {
    const float* x  = (const float*)d_in[0];
    const float* fr = (const float*)d_in[2];
    const float* wr = (const float*)d_in[3];
    const float* g1 = (const float*)d_in[4];
    const float* wq = (const float*)d_in[5];
    const float* wk = (const float*)d_in[6];
    const float* wv = (const float*)d_in[7];
    const float* wo = (const float*)d_in[8];
    const float* g2 = (const float*)d_in[9];
    const float* w1 = (const float*)d_in[10];
    const float* w3 = (const float*)d_in[11];
    const float* w2 = (const float*)d_in[12];
    float* out = (float*)d_out;

    char* ws = (char*)d_ws;
    size_t off = 0;
    auto take = [&](size_t bytes) -> char* {
        char* p = ws + off;
        off += (bytes + 255) & ~(size_t)255;
        return p;
    };
    int*   sel    = (int*)take((size_t)NB * NT * 4);
    float* rw     = (float*)take((size_t)NB * NT * 4);
    float* logits = (float*)take((size_t)NB * NS * 4);
    float* xf     = (float*)take((size_t)NB * NT * ND * 4);
    bf16*  hbuf   = (bf16*)take((size_t)NB * NT * ND * 2);
    bf16*  wq_t   = (bf16*)take((size_t)ND * ND * 2);
    bf16*  wk_t   = (bf16*)take((size_t)ND * ND * 2);
    bf16*  wv_t   = (bf16*)take((size_t)ND * ND * 2);
    bf16*  wo_t   = (bf16*)take((size_t)ND * ND * 2);
    bf16*  Obuf   = (bf16*)take((size_t)NB * NT * ND * 2);
    char* xr = ws + off;
    bf16* Qlin = (bf16*)xr;
    bf16* Klin = Qlin + (size_t)NB * NT * ND;
    bf16* Vlin = Klin + (size_t)NB * NT * ND;
    bf16* Qr   = Vlin + (size_t)NB * NT * ND;
    bf16* Kr   = Qr + (size_t)NB * NT * ND;
    bf16* Vt   = Kr + (size_t)NB * NT * ND;
    float* scores = (float*)(Vt + (size_t)NB * NT * ND);
    bf16*  P      = (bf16*)(scores + (size_t)NH * NT * NT);
    bf16* w1_t  = (bf16*)xr;
    bf16* w3_t  = w1_t + (size_t)ND * NF;
    bf16* w2_t  = w3_t + (size_t)ND * NF;
    bf16* inter = w2_t + (size_t)ND * NF;

    router_k<<<NB * NS, 256, 0, stream>>>(x, wr, logits);
    topk_k<<<NB, 1024, 0, stream>>>(logits, sel, rw);
    gather_k<<<(NB * NT * ND / 4) / 256, 256, 0, stream>>>(x, sel, xf);
    rmsnorm_k<<<NB * NT, 256, 0, stream>>>(xf, g1, hbuf);

    dim3 tg(ND / 32, ND / 32);
    transpose_to_bf16<<<tg, 256, 0, stream>>>(wq, wq_t, ND, ND);
    transpose_to_bf16<<<tg, 256, 0, stream>>>(wk, wk_t, ND, ND);
    transpose_to_bf16<<<tg, 256, 0, stream>>>(wv, wv_t, ND, ND);
    transpose_to_bf16<<<tg, 256, 0, stream>>>(wo, wo_t, ND, ND);

    dim3 gp(ND / 128, (NB * NT) / 128, 1);
    gemm_bt<0><<<gp, 256, 0, stream>>>(hbuf, ND, 0, wq_t, ND, 0, Qlin, 0, ND,
                                       ND, 1.0f, nullptr, nullptr, nullptr, nullptr);
    gemm_bt<0><<<gp, 256, 0, stream>>>(hbuf, ND, 0, wk_t, ND, 0, Klin, 0, ND,
                                       ND, 1.0f, nullptr, nullptr, nullptr, nullptr);
    gemm_bt<0><<<gp, 256, 0, stream>>>(hbuf, ND, 0, wv_t, ND, 0, Vlin, 0, ND,
                                       ND, 1.0f, nullptr, nullptr, nullptr, nullptr);
    rope_k<<<(NB * NT * NH * 64) / 256, 256, 0, stream>>>(Qlin, Klin, Vlin, fr,
                                                          Qr, Kr, Vt);

    const float scal = 0.08838834764831845f;   // 1/sqrt(128)
    for (int bb = 0; bb < NB; bb++) {
        dim3 gs(NT / 128, NT / 128, NH);
        gemm_bt<1><<<gs, 256, 0, stream>>>(
            Qr + (size_t)bb * NH * NT * NHD, NHD, (long long)NT * NHD,
            Kr + (size_t)bb * NH * NT * NHD, NHD, (long long)NT * NHD,
            scores, (long long)NT * NT, NT, NHD, scal,
            nullptr, nullptr, nullptr, nullptr);
        softmax_k<<<NH * NT, 256, 0, stream>>>(scores, P);
        dim3 gv(NHD / 128, NT / 128, NH);
        gemm_bt<0><<<gv, 256, 0, stream>>>(
            P, NT, (long long)NT * NT,
            Vt + (size_t)bb * NH * NHD * NT, NT, (long long)NHD * NT,
            Obuf + (size_t)bb * NT * ND, NHD, ND, NT, 1.0f,
            nullptr, nullptr, nullptr, nullptr);
    }

    gemm_bt<2><<<gp, 256, 0, stream>>>(Obuf, ND, 0, wo_t, ND, 0, xf, 0, ND,
                                       ND, 1.0f, nullptr, nullptr, nullptr, nullptr);

    rmsnorm_k<<<NB * NT, 256, 0, stream>>>(xf, g2, hbuf);

    transpose_to_bf16<<<dim3(NF / 32, ND / 32), 256, 0, stream>>>(w1, w1_t, ND, NF);
    transpose_to_bf16<<<dim3(NF / 32, ND / 32), 256, 0, stream>>>(w3, w3_t, ND, NF);
    transpose_to_bf16<<<dim3(ND / 32, NF / 32), 256, 0, stream>>>(w2, w2_t, NF, ND);

    dim3 gf(NF / 128, (NB * NT) / 128, 1);
    gemm_bt<3><<<gf, 256, 0, stream>>>(hbuf, ND, 0, w1_t, ND, 0, inter, 0, NF,
                                       ND, 1.0f, nullptr, nullptr, nullptr, nullptr);
    gemm_bt<4><<<gf, 256, 0, stream>>>(hbuf, ND, 0, w3_t, ND, 0, inter, 0, NF,
                                       ND, 1.0f, nullptr, nullptr, nullptr, nullptr);

    copy_k<<<8192, 256, 0, stream>>>((const float4*)x, (float4*)out,
                                     (long long)NB * NS * ND / 4);
    gemm_bt<5><<<gp, 256, 0, stream>>>(inter, NF, 0, w2_t, NF, 0, nullptr, 0, ND,
                                       NF, 1.0f, xf, sel, rw, out);
}